// Round 9
// baseline (803.151 us; speedup 1.0000x reference)
//
#include <hip/hip_runtime.h>
#include <hip/hip_fp16.h>

#define N_NODES 50000
#define N_EDGES 800000
#define E_TOT   (N_EDGES + N_NODES)   // with self loops: 850000
#define IN_F    129
#define HID     32
#define HEADS   4
#define F1      (HEADS * HID)     // 128
#define NCLS    40
#define F2      (HEADS * NCLS)    // 160
#define NEG     0.2f
#define BN_EPS  1e-5f
#define NB      ((N_NODES + 255) / 256)   // 196 buckets (256 nodes each)
#define BCAP    6144                      // bucket capacity (E[4352], 6sigma~4740)
#define LOG2E   1.4426950408889634f

typedef __attribute__((ext_vector_type(8))) short bf16x8;
typedef __attribute__((ext_vector_type(4))) float f32x4;

#define P1_ELEMS (8 * 4 * 64 * 8)    // 16384: W1 fragments (8 ntiles x 4 kchunks)
#define P2_ELEMS (10 * 4 * 64 * 8)   // 20480: W2 fragments (10 ntiles x 4 kchunks)

__device__ __forceinline__ unsigned short bf16_rne(float f) {
  unsigned u = __float_as_uint(f);
  u = (u + 0x7FFFu + ((u >> 16) & 1u)) >> 16;
  return (unsigned short)u;
}
__device__ __forceinline__ float bf16_to_f(unsigned short s) {
  return __uint_as_float(((unsigned)s) << 16);
}
__device__ __forceinline__ unsigned pack_f16(float a, float b) {
  __half2 h = __floats2half2_rn(a, b);
  return *reinterpret_cast<unsigned*>(&h);
}
__device__ __forceinline__ float2 unpack_f16(unsigned u) {
  __half2 h = *reinterpret_cast<__half2*>(&u);
  return __half22float2(h);
}

// ---- pack W1/W2 into MFMA B-fragment layout, hi/lo bf16 split -------------
__global__ __launch_bounds__(256) void packw_kernel(
    const float* __restrict__ W1, const float* __restrict__ W2,
    unsigned short* __restrict__ p1h, unsigned short* __restrict__ p1l,
    unsigned short* __restrict__ p2h, unsigned short* __restrict__ p2l) {
  int e = blockIdx.x * 256 + threadIdx.x;
  if (e < P1_ELEMS) {
    int i = e & 7, l = (e >> 3) & 63, c = (e >> 9) & 3, t = e >> 11;
    int k = c * 32 + (l >> 4) * 8 + i;
    int col = t * 16 + (l & 15);
    float v = W1[k * F1 + col];
    unsigned short hi = bf16_rne(v);
    p1h[e] = hi;
    p1l[e] = bf16_rne(v - bf16_to_f(hi));
  }
  int e2 = e - P1_ELEMS;
  if (e2 >= 0 && e2 < P2_ELEMS) {
    int i = e2 & 7, l = (e2 >> 3) & 63, c = (e2 >> 9) & 3, t = e2 >> 11;
    int k = c * 32 + (l >> 4) * 8 + i;
    int col = t * 16 + (l & 15);
    float v = W2[k * F2 + col];
    unsigned short hi = bf16_rne(v);
    p2h[e2] = hi;
    p2l[e2] = bf16_rne(v - bf16_to_f(hi));
  }
}

// ---------------- GEMM1 (BN fused, MFMA 3xbf16): [N,129]x[129,128] ---------
__global__ __launch_bounds__(256) void gemm1_kernel(
    const float* __restrict__ x,
    const float* __restrict__ bng, const float* __restrict__ bnb,
    const float* __restrict__ bnm, const float* __restrict__ bnv,
    const unsigned short* __restrict__ p1h, const unsigned short* __restrict__ p1l,
    const float* __restrict__ W1, float* __restrict__ h1,
    unsigned* __restrict__ h1b) {
  __shared__ float scale[IN_F], shift[IN_F];
  int tid = threadIdx.x;
  if (tid < IN_F) {
    float sc = bng[tid] * rsqrtf(bnv[tid] + BN_EPS);
    scale[tid] = sc;
    shift[tid] = bnb[tid] - bnm[tid] * sc;
  }
  __syncthreads();
  int lane = tid & 63, wave = tid >> 6;
  int row0 = blockIdx.x * 64 + wave * 16;
  if (row0 >= N_NODES) return;
  int arow = row0 + (lane & 15);
  int arow_c = arow < N_NODES ? arow : N_NODES - 1;
  int kb = (lane >> 4) * 8;
  const float* xr = x + (size_t)arow_c * IN_F;
  bf16x8 ah[4], al[4];
#pragma unroll
  for (int c = 0; c < 4; c++) {
    int k0 = c * 32 + kb;
#pragma unroll
    for (int i = 0; i < 8; i++) {
      float a = xr[k0 + i] * scale[k0 + i] + shift[k0 + i];
      unsigned short hi = bf16_rne(a);
      ah[c][i] = (short)hi;
      al[c][i] = (short)bf16_rne(a - bf16_to_f(hi));
    }
  }
  int crow_base = row0 + (lane >> 4) * 4;
  float atail[4];
#pragma unroll
  for (int r = 0; r < 4; r++) {
    int rr = crow_base + r;
    rr = rr < N_NODES ? rr : N_NODES - 1;
    atail[r] = x[(size_t)rr * IN_F + 128] * scale[128] + shift[128];
  }
  int col0 = lane & 15;
  for (int t = 0; t < 8; t++) {
    f32x4 acc = {0.f, 0.f, 0.f, 0.f};
#pragma unroll
    for (int c = 0; c < 4; c++) {
      bf16x8 bh = *(const bf16x8*)(p1h + ((t * 4 + c) * 64 + lane) * 8);
      bf16x8 bl = *(const bf16x8*)(p1l + ((t * 4 + c) * 64 + lane) * 8);
      acc = __builtin_amdgcn_mfma_f32_16x16x32_bf16(ah[c], bh, acc, 0, 0, 0);
      acc = __builtin_amdgcn_mfma_f32_16x16x32_bf16(al[c], bh, acc, 0, 0, 0);
      acc = __builtin_amdgcn_mfma_f32_16x16x32_bf16(ah[c], bl, acc, 0, 0, 0);
    }
    int col = t * 16 + col0;
    float wtail = W1[128 * F1 + col];
#pragma unroll
    for (int r = 0; r < 4; r++) {
      float fin = acc[r] + atail[r] * wtail;
      float odd = __shfl(fin, lane + 1);    // partner column value
      int rr = crow_base + r;
      if (rr < N_NODES) {
        h1[(size_t)rr * F1 + col] = fin;
        if ((col0 & 1) == 0)
          h1b[(size_t)rr * (F1 / 2) + (col >> 1)] = pack_f16(fin, odd);
      }
    }
  }
}

// ---------------- GEMM2 (MFMA 3xbf16): [N,128]x[128,160] -------------------
__global__ __launch_bounds__(256) void gemm2_kernel(
    const float* __restrict__ hin,
    const unsigned short* __restrict__ p2h, const unsigned short* __restrict__ p2l,
    float* __restrict__ h2, unsigned* __restrict__ h2b) {
  int tid = threadIdx.x;
  int lane = tid & 63, wave = tid >> 6;
  int row0 = blockIdx.x * 64 + wave * 16;
  if (row0 >= N_NODES) return;
  int arow = row0 + (lane & 15);
  int arow_c = arow < N_NODES ? arow : N_NODES - 1;
  int kb = (lane >> 4) * 8;
  const float* hr = hin + (size_t)arow_c * F1;
  bf16x8 ah[4], al[4];
#pragma unroll
  for (int c = 0; c < 4; c++) {
    float4 v0 = *(const float4*)(hr + c * 32 + kb);
    float4 v1 = *(const float4*)(hr + c * 32 + kb + 4);
    float av[8] = {v0.x, v0.y, v0.z, v0.w, v1.x, v1.y, v1.z, v1.w};
#pragma unroll
    for (int i = 0; i < 8; i++) {
      unsigned short hi = bf16_rne(av[i]);
      ah[c][i] = (short)hi;
      al[c][i] = (short)bf16_rne(av[i] - bf16_to_f(hi));
    }
  }
  int crow_base = row0 + (lane >> 4) * 4;
  int col0 = lane & 15;
  for (int t = 0; t < 10; t++) {
    f32x4 acc = {0.f, 0.f, 0.f, 0.f};
#pragma unroll
    for (int c = 0; c < 4; c++) {
      bf16x8 bh = *(const bf16x8*)(p2h + ((t * 4 + c) * 64 + lane) * 8);
      bf16x8 bl = *(const bf16x8*)(p2l + ((t * 4 + c) * 64 + lane) * 8);
      acc = __builtin_amdgcn_mfma_f32_16x16x32_bf16(ah[c], bh, acc, 0, 0, 0);
      acc = __builtin_amdgcn_mfma_f32_16x16x32_bf16(al[c], bh, acc, 0, 0, 0);
      acc = __builtin_amdgcn_mfma_f32_16x16x32_bf16(ah[c], bl, acc, 0, 0, 0);
    }
    int col = t * 16 + col0;
#pragma unroll
    for (int r = 0; r < 4; r++) {
      int rr = crow_base + r;
      float odd = __shfl(acc[r], lane + 1);
      if (rr < N_NODES) {
        h2[(size_t)rr * F2 + col] = acc[r];
        if ((lane & 1) == 0)
          h2b[(size_t)rr * (F2 / 2) + (col >> 1)] = pack_f16(acc[r], odd);
      }
    }
  }
}

// ---------------- attention scalars (pre-scaled by log2(e)) ----------------
__global__ __launch_bounds__(256) void alpha1_kernel(
    const float* __restrict__ h1, const float* __restrict__ a_src,
    const float* __restrict__ a_dst, float* __restrict__ as,
    float* __restrict__ ad) {
  int t = blockIdx.x * 256 + threadIdx.x;
  if (t >= N_NODES * HEADS) return;
  int n = t >> 2, h = t & 3;
  const float* hp = h1 + (size_t)n * F1 + h * HID;
  const float* sp = a_src + h * HID;
  const float* dp = a_dst + h * HID;
  float s = 0.f, d = 0.f;
#pragma unroll
  for (int c = 0; c < HID; c++) { float v = hp[c]; s += v * sp[c]; d += v * dp[c]; }
  as[t] = s * LOG2E; ad[t] = d * LOG2E;
}

__global__ __launch_bounds__(256) void alpha2_kernel(
    const float* __restrict__ h2, const float* __restrict__ a_src,
    const float* __restrict__ a_dst, float* __restrict__ as,
    float* __restrict__ ad) {
  int t = blockIdx.x * 256 + threadIdx.x;
  if (t >= N_NODES * HEADS) return;
  int n = t >> 2, h = t & 3;
  const float* hp = h2 + (size_t)n * F2 + h * NCLS;
  const float* sp = a_src + h * NCLS;
  const float* dp = a_dst + h * NCLS;
  float s = 0.f, d = 0.f;
#pragma unroll
  for (int c = 0; c < NCLS; c++) { float v = hp[c]; s += v * sp[c]; d += v * dp[c]; }
  as[t] = s * LOG2E; ad[t] = d * LOG2E;
}

// ---------------- CSR build: bucketed, write-amplification-free ------------
// record: (dstlocal:8)<<16 | src:16    (N_NODES < 65536)
__global__ __launch_bounds__(256) void bucket_kernel(
    const int* __restrict__ ei, int* __restrict__ bcnt,
    unsigned* __restrict__ buck) {
  int e = blockIdx.x * 256 + threadIdx.x;
  if (e >= E_TOT) return;
  int src, dst;
  if (e < N_EDGES) { src = ei[e]; dst = ei[N_EDGES + e]; }
  else { src = dst = e - N_EDGES; }
  int b = dst >> 8;
  int pos = atomicAdd(&bcnt[b], 1);
  buck[(size_t)b * BCAP + pos] = ((unsigned)(dst & 255) << 16) | (unsigned)src;
}

__global__ __launch_bounds__(256) void bucketscan_kernel(
    const int* __restrict__ bcnt, int* __restrict__ bbase) {
  __shared__ int sh[256];
  int t = threadIdx.x;
  int v = (t < NB) ? bcnt[t] : 0;
  sh[t] = v;
  __syncthreads();
  for (int o = 1; o < 256; o <<= 1) {
    int u = (t >= o) ? sh[t - o] : 0;
    __syncthreads();
    sh[t] += u;
    __syncthreads();
  }
  if (t < NB) bbase[t] = sh[t] - v;   // exclusive
}

// one block per bucket: LDS hist -> scan (offs) -> LDS scatter -> coalesced out
__global__ __launch_bounds__(256) void build_kernel(
    const int* __restrict__ bcnt, const int* __restrict__ bbase,
    const unsigned* __restrict__ buck,
    int* __restrict__ offs, unsigned short* __restrict__ csr) {
  __shared__ int hist[256];
  __shared__ int scanbuf[256];
  __shared__ unsigned short stage[BCAP];
  int b = blockIdx.x, t = threadIdx.x;
  hist[t] = 0;
  __syncthreads();
  int cnt = bcnt[b];
  int base = bbase[b];
  const unsigned* bp = buck + (size_t)b * BCAP;
  for (int i = t; i < cnt; i += 256)
    atomicAdd(&hist[bp[i] >> 16], 1);
  __syncthreads();
  int v = hist[t];
  scanbuf[t] = v;
  __syncthreads();
  for (int o = 1; o < 256; o <<= 1) {
    int u = (t >= o) ? scanbuf[t - o] : 0;
    __syncthreads();
    scanbuf[t] += u;
    __syncthreads();
  }
  int excl = scanbuf[t] - v;
  int node = b * 256 + t;
  if (node < N_NODES) offs[node] = base + excl;
  if (b == 0 && t == 0) offs[N_NODES] = E_TOT;
  hist[t] = excl;          // reuse as running fill positions
  __syncthreads();
  for (int i = t; i < cnt; i += 256) {
    unsigned rec = bp[i];
    int p = atomicAdd(&hist[rec >> 16], 1);
    stage[p] = (unsigned short)(rec & 0xFFFFu);
  }
  __syncthreads();
  for (int i = t; i < cnt; i += 256)
    csr[base + i] = stage[i];
}

// ---- aggregation layer 1: fp16-packed gather, u16 csr, unroll 8 -----------
__global__ __launch_bounds__(256) void agg1_kernel(
    const unsigned* __restrict__ h1b, const float* __restrict__ as,
    const float* __restrict__ ad, const int* __restrict__ off,
    const unsigned short* __restrict__ csr, const float* __restrict__ b1,
    float* __restrict__ out) {
  int gw = (blockIdx.x * blockDim.x + threadIdx.x) >> 6;
  int lane = threadIdx.x & 63;
  if (gw >= N_NODES) return;
  int base = off[gw];
  int deg  = off[gw + 1] - base;
  int h = lane & 3;
  int g = lane >> 4;          // head of channels 2l, 2l+1
  float adh = ad[gw * 4 + h];
  float s = 0.f, acc0 = 0.f, acc1 = 0.f;
  int j = 0;
  for (; j + 8 <= deg; j += 8) {
    int sr[8];
#pragma unroll
    for (int u = 0; u < 8; u++) sr[u] = csr[base + j + u];
    float av[8];
#pragma unroll
    for (int u = 0; u < 8; u++) av[u] = as[sr[u]*4 + h];
    unsigned uv[8];
#pragma unroll
    for (int u = 0; u < 8; u++)
      uv[u] = h1b[(size_t)sr[u] * (F1/2) + lane];
    float w[8];
#pragma unroll
    for (int u = 0; u < 8; u++) {
      float v = av[u] + adh;
      v = fmaxf(v, NEG * v);                 // leakyrelu (log2-domain)
      w[u] = __builtin_amdgcn_exp2f(v);
      s += w[u];
    }
#pragma unroll
    for (int u = 0; u < 8; u++) {
      float wg = __shfl(w[u], g);
      float2 xv = unpack_f16(uv[u]);
      acc0 += wg * xv.x;
      acc1 += wg * xv.y;
    }
  }
  for (; j < deg; j++) {
    int src = csr[base + j];
    float v = as[src*4 + h] + adh;
    v = fmaxf(v, NEG * v);
    float w = __builtin_amdgcn_exp2f(v);
    s += w;
    unsigned uv = h1b[(size_t)src * (F1/2) + lane];
    float wg = __shfl(w, g);
    float2 xv = unpack_f16(uv);
    acc0 += wg * xv.x;
    acc1 += wg * xv.y;
  }
  float sg = __shfl(s, g);
  float2 bp = *(const float2*)&b1[2*lane];
  float o0 = acc0 / sg + bp.x;
  float o1 = acc1 / sg + bp.y;
  o0 = o0 > 0.f ? o0 : expm1f(o0);   // ELU fused
  o1 = o1 > 0.f ? o1 : expm1f(o1);
  *(float2*)&out[(size_t)gw * F1 + 2*lane] = make_float2(o0, o1);
}

// ---- aggregation layer 2: fp16-packed gather, u16 csr, unroll 8 -----------
__global__ __launch_bounds__(256) void agg2_kernel(
    const unsigned* __restrict__ h2b, const float* __restrict__ as,
    const float* __restrict__ ad, const int* __restrict__ off,
    const unsigned short* __restrict__ csr, const float* __restrict__ b2,
    float* __restrict__ out) {
  int gw = (blockIdx.x * blockDim.x + threadIdx.x) >> 6;
  int lane = threadIdx.x & 63;
  if (gw >= N_NODES) return;
  int base = off[gw];
  int deg  = off[gw + 1] - base;
  int h  = lane & 3;
  int gA = lane / 20;
  bool third = lane < 16;
  float adh = ad[gw * 4 + h];
  float s = 0.f, a0 = 0.f, a1 = 0.f, a2 = 0.f, a3 = 0.f;
  int j = 0;
  for (; j + 8 <= deg; j += 8) {
    int sr[8];
#pragma unroll
    for (int u = 0; u < 8; u++) sr[u] = csr[base + j + u];
    float av[8];
#pragma unroll
    for (int u = 0; u < 8; u++) av[u] = as[sr[u]*4 + h];
    unsigned ua[8], ub[8];
#pragma unroll
    for (int u = 0; u < 8; u++) {
      const unsigned* r = h2b + (size_t)sr[u] * (F2/2);
      ua[u] = r[lane];
      ub[u] = third ? r[64 + lane] : 0u;
    }
    float w[8];
#pragma unroll
    for (int u = 0; u < 8; u++) {
      float v = av[u] + adh;
      v = fmaxf(v, NEG * v);
      w[u] = __builtin_amdgcn_exp2f(v);
      s += w[u];
    }
#pragma unroll
    for (int u = 0; u < 8; u++) {
      float wA = __shfl(w[u], gA);
      float w3 = __shfl(w[u], 3);
      float2 fa = unpack_f16(ua[u]);
      float2 fb = unpack_f16(ub[u]);
      a0 += wA * fa.x;
      a1 += wA * fa.y;
      a2 += w3 * fb.x;
      a3 += w3 * fb.y;
    }
  }
  for (; j < deg; j++) {
    int src = csr[base + j];
    float v = as[src*4 + h] + adh;
    v = fmaxf(v, NEG * v);
    float w = __builtin_amdgcn_exp2f(v);
    s += w;
    const unsigned* r = h2b + (size_t)src * (F2/2);
    unsigned ua = r[lane];
    unsigned ub = third ? r[64 + lane] : 0u;
    float wA = __shfl(w, gA);
    float w3 = __shfl(w, 3);
    float2 fa = unpack_f16(ua);
    float2 fb = unpack_f16(ub);
    a0 += wA * fa.x;
    a1 += wA * fa.y;
    a2 += w3 * fb.x;
    a3 += w3 * fb.y;
  }
  float sA = __shfl(s, gA), s3 = __shfl(s, 3);
  float2 bp = *(const float2*)&b2[2*lane];
  *(float2*)&out[(size_t)gw * F2 + 2*lane] =
      make_float2(a0/sA + bp.x, a1/sA + bp.y);
  if (third) {
    float2 bq = *(const float2*)&b2[128 + 2*lane];
    *(float2*)&out[(size_t)gw * F2 + 128 + 2*lane] =
        make_float2(a2/s3 + bq.x, a3/s3 + bq.y);
  }
}

extern "C" void kernel_launch(void* const* d_in, const int* in_sizes, int n_in,
                              void* d_out, int out_size, void* d_ws, size_t ws_size,
                              hipStream_t stream) {
  const float* x   = (const float*)d_in[0];
  const int*   ei  = (const int*)d_in[1];
  const float* bng = (const float*)d_in[2];
  const float* bnb = (const float*)d_in[3];
  const float* bnm = (const float*)d_in[4];
  const float* bnv = (const float*)d_in[5];
  const float* W1  = (const float*)d_in[6];
  const float* a1s = (const float*)d_in[7];
  const float* a1d = (const float*)d_in[8];
  const float* b1  = (const float*)d_in[9];
  const float* W2  = (const float*)d_in[10];
  const float* a2s = (const float*)d_in[11];
  const float* a2d = (const float*)d_in[12];
  const float* b2  = (const float*)d_in[13];
  float* out = (float*)d_out;

  char* ws = (char*)d_ws;
  size_t p = 0;
  auto alloc = [&](size_t bytes) -> char* {
    char* r = ws + p;
    p += (bytes + 255) & ~(size_t)255;
    return r;
  };
  float* h1   = (float*)alloc(sizeof(float) * (size_t)N_NODES * F1);   // 25.6MB
  float* h1a  = (float*)alloc(sizeof(float) * (size_t)N_NODES * F1);   // 25.6MB
  float* h2   = (float*)alloc(sizeof(float) * (size_t)N_NODES * F2);   // 32MB
  unsigned* h1b = (unsigned*)alloc(sizeof(unsigned) * (size_t)N_NODES * (F1/2)); // 12.8MB
  float* as1  = (float*)alloc(sizeof(float) * (size_t)N_NODES * HEADS);
  float* ad1  = (float*)alloc(sizeof(float) * (size_t)N_NODES * HEADS);
  float* as2  = (float*)alloc(sizeof(float) * (size_t)N_NODES * HEADS);
  float* ad2  = (float*)alloc(sizeof(float) * (size_t)N_NODES * HEADS);
  int* bcnt   = (int*)alloc(sizeof(int) * NB);
  int* bbase  = (int*)alloc(sizeof(int) * NB);
  unsigned* buck = (unsigned*)alloc(sizeof(unsigned) * (size_t)NB * BCAP); // 4.8MB
  int* offs   = (int*)alloc(sizeof(int) * (N_NODES + 1));
  unsigned short* csr = (unsigned short*)alloc(sizeof(unsigned short) * E_TOT); // 1.7MB
  unsigned short* p1h = (unsigned short*)alloc(sizeof(unsigned short) * P1_ELEMS);
  unsigned short* p1l = (unsigned short*)alloc(sizeof(unsigned short) * P1_ELEMS);
  unsigned short* p2h = (unsigned short*)alloc(sizeof(unsigned short) * P2_ELEMS);
  unsigned short* p2l = (unsigned short*)alloc(sizeof(unsigned short) * P2_ELEMS);
  // fp16 copy of h2 for agg2's gather; h1 dead once gemm2 runs -> alias
  unsigned* h2b = (unsigned*)h1;   // N * 80 u32 = 16MB < 25.6MB

  hipMemsetAsync(bcnt, 0, sizeof(int) * NB, stream);

  // weight packing (independent of everything else)
  packw_kernel<<<(P1_ELEMS + P2_ELEMS + 255) / 256, 256, 0, stream>>>(
      W1, W2, p1h, p1l, p2h, p2l);

  // CSR build (bucketed)
  bucket_kernel<<<(E_TOT + 255) / 256, 256, 0, stream>>>(ei, bcnt, buck);
  bucketscan_kernel<<<1, 256, 0, stream>>>(bcnt, bbase);
  build_kernel<<<NB, 256, 0, stream>>>(bcnt, bbase, buck, offs, csr);

  // layer 1
  int gblocks = (N_NODES + 63) / 64;   // 782
  gemm1_kernel<<<gblocks, 256, 0, stream>>>(x, bng, bnb, bnm, bnv, p1h, p1l, W1, h1, h1b);
  alpha1_kernel<<<(N_NODES * HEADS + 255) / 256, 256, 0, stream>>>(h1, a1s, a1d, as1, ad1);
  agg1_kernel<<<(N_NODES + 3) / 4, 256, 0, stream>>>(h1b, as1, ad1, offs, csr, b1, h1a);

  // layer 2
  gemm2_kernel<<<gblocks, 256, 0, stream>>>(h1a, p2h, p2l, h2, h2b);
  alpha2_kernel<<<(N_NODES * HEADS + 255) / 256, 256, 0, stream>>>(h2, a2s, a2d, as2, ad2);
  agg2_kernel<<<(N_NODES + 3) / 4, 256, 0, stream>>>(h2b, as2, ad2, offs, csr, b2, out);
}